// Round 1
// baseline (26.096 us; speedup 1.0000x reference)
//
#include <hip/hip_runtime.h>
#include <math.h>

// Problem constants (fixed by setup_inputs)
#define B 4
#define H 64
#define W 64
#define C 256
#define R 128
#define PH 7
#define PW 7

__global__ __launch_bounds__(256) void roi_pool_kernel(
    const float* __restrict__ fm,      // [B,H,W,C]
    const float* __restrict__ rois,    // [B,R,4] = x1,y1,x2,y2
    float* __restrict__ out)           // [B,R,PH,PW,C]
{
    const int wave = threadIdx.x >> 6;
    const int lane = threadIdx.x & 63;
    const int cell = blockIdx.x * 4 + wave;   // 0 .. B*R*PH*PW - 1

    // decode (b, r, p, q) from cell, row-major [B,R,PH,PW]
    const int q = cell % PW;
    int t = cell / PW;
    const int p = t % PH;
    t /= PH;
    const int r = t % R;
    const int b = t / R;

    const float* roi = rois + (size_t)(b * R + r) * 4;
    const float x1 = roi[0], y1 = roi[1], x2 = roi[2], y2 = roi[3];

    // jnp.round = round-half-to-even -> rintf under default RN mode
    int ws = max((int)rintf(x1), 0);
    int hs = max((int)rintf(y1), 0);
    int we = min((int)rintf(x2), W);
    int he = min((int)rintf(y2), H);

    // TF reshape quirk: out[b,r,p,q,:] = max over h-bin q, w-bin p.
    // Bin bounds: replicate exact fp32 arithmetic of the reference.
    const float hstep = (float)(he - hs) / 7.0f;
    const float wstep = (float)(we - ws) / 7.0f;
    const int hlo = hs + (int)((float)q * hstep);
    const int hhi = (q < PH - 1) ? (hs + (int)((float)(q + 1) * hstep)) : he;
    const int wlo = ws + (int)((float)p * wstep);
    const int whi = (p < PW - 1) ? (ws + (int)((float)(p + 1) * wstep)) : we;

    float4 acc = make_float4(-INFINITY, -INFINITY, -INFINITY, -INFINITY);
    const int cbase = lane * 4;   // 4 channels per lane, contiguous

    for (int h = hlo; h < hhi; ++h) {
        const float* rowp = fm + ((size_t)(b * H + h) * W) * C + cbase;
        for (int w = wlo; w < whi; ++w) {
            const float4 v = *(const float4*)(rowp + (size_t)w * C);
            acc.x = fmaxf(acc.x, v.x);
            acc.y = fmaxf(acc.y, v.y);
            acc.z = fmaxf(acc.z, v.z);
            acc.w = fmaxf(acc.w, v.w);
        }
    }

    float4* op = (float4*)(out + (size_t)cell * C + cbase);
    *op = acc;
}

extern "C" void kernel_launch(void* const* d_in, const int* in_sizes, int n_in,
                              void* d_out, int out_size, void* d_ws, size_t ws_size,
                              hipStream_t stream) {
    const float* fm   = (const float*)d_in[0];
    const float* rois = (const float*)d_in[1];
    float* out = (float*)d_out;

    const int total_cells = B * R * PH * PW;          // 25088
    const int grid = total_cells / 4;                  // 6272 blocks, 4 waves each
    roi_pool_kernel<<<grid, 256, 0, stream>>>(fm, rois, out);
}

// Round 2
// 21.803 us; speedup vs baseline: 1.1969x; 1.1969x over previous
//
#include <hip/hip_runtime.h>
#include <math.h>

// Problem constants (fixed by setup_inputs)
#define B 4
#define H 64
#define W 64
#define C 256
#define R 128
#define PH 7
#define PW 7

// cells per batch = R*PH*PW = 6272; blocks per batch = 1568; per half-batch = 784
#define CELLS_TOTAL (B * R * PH * PW)   // 25088
#define BLOCKS_TOTAL (CELLS_TOTAL / 4)  // 6272
#define BLOCKS_PER_HALF 784             // 6272 / 8

__global__ __launch_bounds__(256) void roi_pool_kernel(
    const float* __restrict__ fm,      // [B,H,W,C]
    const float* __restrict__ rois,    // [B,R,4] = x1,y1,x2,y2
    float* __restrict__ out)           // [B,R,PH,PW,C]
{
    const int wave = threadIdx.x >> 6;
    const int lane = threadIdx.x & 63;

    // XCD-aware swizzle: blockIdx % 8 = XCD (round-robin dispatch).
    // Pin each XCD to one batch b (2 XCDs per batch) so the 4.2 MB per-batch
    // fm slice stays resident in that XCD's 4 MiB L2.
    const int xcd  = blockIdx.x & 7;        // 0..7
    const int slot = blockIdx.x >> 3;       // 0..783
    const int b    = xcd >> 1;              // 0..3
    const int half = xcd & 1;               // 0..1
    const int cell_in_b = (half * BLOCKS_PER_HALF + slot) * 4 + wave;  // 0..6271

    // decode (r, p, q) from cell_in_b, row-major [R,PH,PW]
    const int q = cell_in_b % PW;
    int t = cell_in_b / PW;
    const int p = t % PH;
    const int r = t / PH;

    const float* roi = rois + (size_t)(b * R + r) * 4;
    const float x1 = roi[0], y1 = roi[1], x2 = roi[2], y2 = roi[3];

    // jnp.round = round-half-to-even -> rintf under default RN mode
    int ws = max((int)rintf(x1), 0);
    int hs = max((int)rintf(y1), 0);
    int we = min((int)rintf(x2), W);
    int he = min((int)rintf(y2), H);

    // TF reshape quirk: out[b,r,p,q,:] = max over h-bin q, w-bin p.
    // Bin bounds: replicate exact fp32 arithmetic of the reference.
    const float hstep = (float)(he - hs) / 7.0f;
    const float wstep = (float)(we - ws) / 7.0f;
    const int hlo = hs + (int)((float)q * hstep);
    const int hhi = (q < PH - 1) ? (hs + (int)((float)(q + 1) * hstep)) : he;
    const int wlo = ws + (int)((float)p * wstep);
    const int whi = (p < PW - 1) ? (ws + (int)((float)(p + 1) * wstep)) : we;

    const int nw = whi - wlo;              // >= 1 (no empty bins by construction)
    const int nh = hhi - hlo;

    float4 acc = make_float4(-INFINITY, -INFINITY, -INFINITY, -INFINITY);
    const int cbase = lane * 4;            // 4 contiguous channels per lane

    // Flattened visit loop with a 2-deep software pipeline (2 loads in flight).
    const float* pcur = fm + ((size_t)(b * H + hlo) * W + wlo) * C + cbase;
    const size_t row_step = (size_t)(W - nw) * C;  // advance from end of row to next row start

    int h = 0, w = 0;
    const float* pnext = pcur;
    float4 v = *(const float4*)pnext;
    for (;;) {
        // advance (h,w)
        ++w;
        if (w == nw) { w = 0; ++h; pnext += row_step * 0; }  // placeholder, fixed below
        // recompute pointer advance properly:
        // (we advance pnext before the branch resolution)
        if (w == 0) pnext += (size_t)C + row_step; else pnext += C;
        if (h == nh) {
            acc.x = fmaxf(acc.x, v.x);
            acc.y = fmaxf(acc.y, v.y);
            acc.z = fmaxf(acc.z, v.z);
            acc.w = fmaxf(acc.w, v.w);
            break;
        }
        float4 nv = *(const float4*)pnext;
        acc.x = fmaxf(acc.x, v.x);
        acc.y = fmaxf(acc.y, v.y);
        acc.z = fmaxf(acc.z, v.z);
        acc.w = fmaxf(acc.w, v.w);
        v = nv;
    }

    const int cell = ((b * R + r) * PH + p) * PW + q;
    float4* op = (float4*)(out + (size_t)cell * C + cbase);
    *op = acc;
}

extern "C" void kernel_launch(void* const* d_in, const int* in_sizes, int n_in,
                              void* d_out, int out_size, void* d_ws, size_t ws_size,
                              hipStream_t stream) {
    const float* fm   = (const float*)d_in[0];
    const float* rois = (const float*)d_in[1];
    float* out = (float*)d_out;

    roi_pool_kernel<<<BLOCKS_TOTAL, 256, 0, stream>>>(fm, rois, out);
}

// Round 4
// 15.334 us; speedup vs baseline: 1.7018x; 1.4219x over previous
//
#include <hip/hip_runtime.h>
#include <math.h>

// Problem constants (fixed by setup_inputs)
#define B 4
#define H 64
#define W 64
#define C 256
#define R 128
#define PH 7
#define PW 7

#define CELLS_TOTAL (B * R * PH * PW)   // 25088
#define BLOCKS_TOTAL (CELLS_TOTAL / 4)  // 6272
#define BLOCKS_PER_HALF 784             // 6272 / 8

typedef float f32x4 __attribute__((ext_vector_type(4)));

__global__ __launch_bounds__(256) void roi_pool_kernel(
    const float* __restrict__ fm,      // [B,H,W,C]
    const float* __restrict__ rois,    // [B,R,4] = x1,y1,x2,y2
    float* __restrict__ out)           // [B,R,PH,PW,C]
{
    const int wave = threadIdx.x >> 6;
    const int lane = threadIdx.x & 63;

    // XCD-aware swizzle: blockIdx % 8 = XCD (round-robin dispatch).
    // Pin each XCD to one batch b (2 XCDs per batch) so the 4.2 MB per-batch
    // fm slice stays resident in that XCD's 4 MiB L2.
    const int xcd  = blockIdx.x & 7;        // 0..7
    const int slot = blockIdx.x >> 3;       // 0..783
    const int b    = xcd >> 1;              // 0..3
    const int half = xcd & 1;               // 0..1
    const int cell_in_b = (half * BLOCKS_PER_HALF + slot) * 4 + wave;  // 0..6271

    // decode (r, p, q) from cell_in_b, row-major [R,PH,PW]
    const int q = cell_in_b % PW;
    int t = cell_in_b / PW;
    const int p = t % PH;
    const int r = t / PH;

    // Scalarize the ROI fetch: index is wave-uniform -> s_load path.
    const int ridx = __builtin_amdgcn_readfirstlane(b * R + r);
    const float* roi = rois + (size_t)ridx * 4;
    const float x1 = roi[0], y1 = roi[1], x2 = roi[2], y2 = roi[3];

    // jnp.round = round-half-to-even -> rintf under default RN mode
    int ws = max((int)rintf(x1), 0);
    int hs = max((int)rintf(y1), 0);
    int we = min((int)rintf(x2), W);
    int he = min((int)rintf(y2), H);

    // TF reshape quirk: out[b,r,p,q,:] = max over h-bin q, w-bin p.
    // Replicate exact fp32 arithmetic of the reference.
    const float hstep = (float)(he - hs) / 7.0f;
    const float wstep = (float)(we - ws) / 7.0f;
    const int hlo = hs + (int)((float)q * hstep);
    const int hhi = (q < PH - 1) ? (hs + (int)((float)(q + 1) * hstep)) : he;
    const int wlo = ws + (int)((float)p * wstep);
    const int whi = (p < PW - 1) ? (ws + (int)((float)(p + 1) * wstep)) : we;

    const int nw = whi - wlo;              // >= 1 (no empty bins by construction)
    const int nh = hhi - hlo;
    const int n  = nh * nw;                // total (h,w) visits, wave-uniform

    const float* gp = fm + ((size_t)(b * H + hlo) * W + wlo) * C + lane * 4;
    int gw = 0;
    const size_t rstep = (size_t)(W - nw + 1) * C;  // last elem of row -> first of next row

    f32x4 acc = { -INFINITY, -INFINITY, -INFINITY, -INFINITY };

#define LOADV(dst) (dst) = *(const f32x4*)gp
#define ADV() { if (++gw == nw) { gw = 0; gp += rstep; } else { gp += (size_t)C; } }
#define FM(vv) { acc.x = fmaxf(acc.x, (vv).x); acc.y = fmaxf(acc.y, (vv).y); \
                 acc.z = fmaxf(acc.z, (vv).z); acc.w = fmaxf(acc.w, (vv).w); }

    if (n >= 4) {
        // 4-deep rotating software pipeline, exactly n loads.
        f32x4 v0, v1, v2, v3;
        LOADV(v0); ADV(); LOADV(v1); ADV(); LOADV(v2); ADV(); LOADV(v3); ADV();
        int k = n - 4;
        while (k >= 4) {
            FM(v0); LOADV(v0); ADV();
            FM(v1); LOADV(v1); ADV();
            FM(v2); LOADV(v2); ADV();
            FM(v3); LOADV(v3); ADV();
            k -= 4;
        }
        // tail: k in [0,3] remaining loads; fmax is commutative so slot order
        // doesn't matter — every slot gets drained at the end.
        if (k > 0) { FM(v0); LOADV(v0); ADV(); }
        if (k > 1) { FM(v1); LOADV(v1); ADV(); }
        if (k > 2) { FM(v2); LOADV(v2); ADV(); }
        FM(v0); FM(v1); FM(v2); FM(v3);
    } else {
        for (int i = 0; i < n; ++i) {
            f32x4 v; LOADV(v); ADV(); FM(v);
        }
    }

    // Non-temporal store: out (25.7 MB) is write-once; keep it from evicting
    // the fm slice out of the per-XCD L2.
    const int cell = ((b * R + r) * PH + p) * PW + q;
    float* op = out + (size_t)cell * C + lane * 4;
    __builtin_nontemporal_store(acc, (f32x4*)op);
}

extern "C" void kernel_launch(void* const* d_in, const int* in_sizes, int n_in,
                              void* d_out, int out_size, void* d_ws, size_t ws_size,
                              hipStream_t stream) {
    const float* fm   = (const float*)d_in[0];
    const float* rois = (const float*)d_in[1];
    float* out = (float*)d_out;

    roi_pool_kernel<<<BLOCKS_TOTAL, 256, 0, stream>>>(fm, rois, out);
}